// Round 3
// baseline (232.955 us; speedup 1.0000x reference)
//
#include <hip/hip_runtime.h>
#include <stdint.h>
#include <math.h>

// LSTMConv via MFMA, single-barrier-per-step pipeline.
// gates(512x64) = W(512x192) @ [x;h](192x64), mfma_f32_16x16x32_bf16.
// Weights (gate W, FC W, fc_b) persistent in VGPRs. [x;h] double-buffered
// in LDS: step t reads buf[t&1]={x_t,h_{t-1}}, writes h_t and gathered
// x_{t+1} into buf[t&1^1]; ONE __syncthreads per step. Gather loads for
// t+1 issued at the top of step t (latency hidden under A+U compute).
// FC for step t runs at the top of step t+1 (reads buf after barrier).

#define T_STEPS 32
#define C_IN    64
#define HID     128
#define OUT_F   64
#define BP      64
#define NBLK    256            // 16384 / BP
#define NTHR    512            // 8 waves
#define PADK    196            // xh row stride (bf16): k 0..63 = x, 64..191 = h

typedef __attribute__((ext_vector_type(8))) short short8_t;
typedef __attribute__((ext_vector_type(4))) short short4_t;
typedef __attribute__((ext_vector_type(4))) float float4_t;

__device__ __forceinline__ short f2bf(float f) {
    uint32_t u = __builtin_bit_cast(uint32_t, f);
    u += 0x7fff + ((u >> 16) & 1);   // RNE
    return (short)(u >> 16);
}
__device__ __forceinline__ float sigm(float x) {
    return __builtin_amdgcn_rcpf(1.0f + __expf(-x));
}
__device__ __forceinline__ float tanh_(float x) {
    float ax = fabsf(x);
    float e  = __expf(-2.0f * ax);
    float t  = (1.0f - e) * __builtin_amdgcn_rcpf(1.0f + e);
    return copysignf(t, x);
}

__global__ __launch_bounds__(NTHR, 2) void lstmconv_mfma(
    const float* __restrict__ feats,
    const float* __restrict__ W_ih,
    const float* __restrict__ W_hh,
    const float* __restrict__ b_ih,
    const float* __restrict__ b_hh,
    const float* __restrict__ fc_w,
    const float* __restrict__ fc_b,
    float* __restrict__ out)
{
    __shared__ __align__(16) short xh[2][BP][PADK];   // 50.2 KB
    __shared__ __align__(16) float bias_s[4 * HID];   // 2 KB

    const int tid  = threadIdx.x;
    const int lane = tid & 63;
    const int w    = tid >> 6;       // wave 0..7; owns gate rows 16w..16w+16
    const int i16  = lane & 15;
    const int g4   = lane >> 4;
    const int p0   = blockIdx.x * BP;

    // ---------- one-time init ----------
    for (int i = tid; i < 2 * BP * PADK / 2; i += NTHR)
        ((uint32_t*)xh)[i] = 0u;                     // h region of buf0 must be 0
    bias_s[tid] = b_ih[tid] + b_hh[tid];             // 512 == NTHR

    // Gate-W fragments (A operand), persistent: wfrag[gate][ktile]
    // row = 128*gi + 16*w + i16 ; k = 32*kt + 8*g4 + e  (kt<2 -> W_ih)
    short8_t wfrag[4][6];
    #pragma unroll
    for (int gi = 0; gi < 4; ++gi) {
        int row = 128 * gi + 16 * w + i16;
        #pragma unroll
        for (int kt = 0; kt < 6; ++kt) {
            int kk = 32 * kt + 8 * g4;
            const float* src = (kt < 2) ? &W_ih[row * C_IN + kk]
                                        : &W_hh[row * HID + (kk - 64)];
            short8_t f;
            #pragma unroll
            for (int e = 0; e < 8; ++e) f[e] = f2bf(src[e]);
            wfrag[gi][kt] = f;
        }
    }

    // FC: wave handles out rows 16*m2..+16 (m2=w&3), n-tiles {ntb, ntb+1}.
    const int m2  = w & 3;
    const int ntb = (w >> 2) << 1;
    short8_t fcfrag[4];
    #pragma unroll
    for (int kt = 0; kt < 4; ++kt) {
        int kk = 32 * kt + 8 * g4;
        const float* src = &fc_w[(16 * m2 + i16) * HID + kk];
        short8_t f;
        #pragma unroll
        for (int e = 0; e < 8; ++e) f[e] = f2bf(src[e]);
        fcfrag[kt] = f;
    }
    const float4_t fcb = *(const float4_t*)&fc_b[16 * m2 + 4 * g4];

    const int prow  = 2 * (p0 >> 7) + 1;
    const int pcol0 = 2 * (p0 & 127) + 1;
    const int gbase = prow * 256 + pcol0 + 2 * lane;  // lane = local p

    // ---------- prologue: gather x_0 into buf0 ----------
    #pragma unroll
    for (int q = 0; q < 8; ++q) {
        int cc = w + 8 * q;
        xh[0][lane][cc] = f2bf(feats[((size_t)cc << 16) + gbase]);
    }

    float4_t c[4];
    #pragma unroll
    for (int nt = 0; nt < 4; ++nt) c[nt] = (float4_t){0.f, 0.f, 0.f, 0.f};

    // FC + store for step tf, reading h from xh[cb]
    auto do_fc = [&](int tf, int cb) {
        float4_t facc[2];
        facc[0] = fcb; facc[1] = fcb;
        #pragma unroll
        for (int kt = 0; kt < 4; ++kt) {
            int kb = 32 * kt + 8 * g4;
            #pragma unroll
            for (int nj = 0; nj < 2; ++nj) {
                int p = 16 * (ntb + nj) + i16;
                union { short8_t v8; short4_t v4[2]; } ub;
                ub.v4[0] = *(const short4_t*)&xh[cb][p][64 + kb];
                ub.v4[1] = *(const short4_t*)&xh[cb][p][64 + kb + 4];
                facc[nj] = __builtin_amdgcn_mfma_f32_16x16x32_bf16(
                    fcfrag[kt], ub.v8, facc[nj], 0, 0, 0);
            }
        }
        #pragma unroll
        for (int nj = 0; nj < 2; ++nj)
            #pragma unroll
            for (int r = 0; r < 4; ++r)
                out[((size_t)(tf * OUT_F + 16 * m2 + 4 * g4 + r) << 14)
                    + p0 + 16 * (ntb + nj) + i16] = facc[nj][r];
    };

    __syncthreads();   // buf0 = {x_0, h_-1=0} ready

    #pragma unroll 2
    for (int t = 0; t < T_STEPS; ++t) {
        const int cur = t & 1;
        const int nxt = cur ^ 1;

        // ---- issue gather loads for x_{t+1} (consumed at Gw below)
        float gr[8];
        if (t < T_STEPS - 1) {
            #pragma unroll
            for (int q = 0; q < 8; ++q) {
                int cc = w + 8 * q;
                gr[q] = feats[((size_t)((t + 1) * C_IN + cc) << 16) + gbase];
            }
        }

        // ---- F(t-1): FC on h_{t-1} (lives in buf[cur])
        if (t > 0) do_fc(t - 1, cur);

        // ---- A: gates = bias + W @ [x_t; h_{t-1}]
        float4_t acc[4][4];
        #pragma unroll
        for (int gi = 0; gi < 4; ++gi) {
            float4_t bv = *(const float4_t*)&bias_s[128 * gi + 16 * w + 4 * g4];
            #pragma unroll
            for (int nt = 0; nt < 4; ++nt) acc[gi][nt] = bv;
        }
        #pragma unroll
        for (int kt = 0; kt < 6; ++kt) {
            short8_t bfrag[4];
            #pragma unroll
            for (int nt = 0; nt < 4; ++nt) {
                int p  = 16 * nt + i16;
                int kb = 32 * kt + 8 * g4;
                union { short8_t v8; short4_t v4[2]; } u;
                u.v4[0] = *(const short4_t*)&xh[cur][p][kb];
                u.v4[1] = *(const short4_t*)&xh[cur][p][kb + 4];
                bfrag[nt] = u.v8;
            }
            #pragma unroll
            for (int gi = 0; gi < 4; ++gi)
                #pragma unroll
                for (int nt = 0; nt < 4; ++nt)
                    acc[gi][nt] = __builtin_amdgcn_mfma_f32_16x16x32_bf16(
                        wfrag[gi][kt], bfrag[nt], acc[gi][nt], 0, 0, 0);
        }

        // ---- U: cell update (gate order i,f,g,o)
        short4_t hpack[4];
        #pragma unroll
        for (int nt = 0; nt < 4; ++nt) {
            float4_t cv = c[nt];
            short4_t hp;
            #pragma unroll
            for (int r = 0; r < 4; ++r) {
                float ig = sigm(acc[0][nt][r]);
                float fg = sigm(acc[1][nt][r]);
                float gg = tanh_(acc[2][nt][r]);
                float og = sigm(acc[3][nt][r]);
                float cn = fg * cv[r] + ig * gg;
                cv[r] = cn;
                hp[r] = f2bf(og * tanh_(cn));
            }
            c[nt] = cv;
            hpack[nt] = hp;
        }

        // ---- W: h_t -> buf[nxt].h  (j = 16w + 4g4 + r)
        #pragma unroll
        for (int nt = 0; nt < 4; ++nt)
            *(short4_t*)&xh[nxt][16 * nt + i16][64 + 16 * w + 4 * g4] = hpack[nt];

        // ---- Gw: x_{t+1} -> buf[nxt].x
        if (t < T_STEPS - 1) {
            #pragma unroll
            for (int q = 0; q < 8; ++q)
                xh[nxt][lane][w + 8 * q] = f2bf(gr[q]);
        }

        __syncthreads();   // buf[nxt] = {x_{t+1}, h_t} complete
    }

    // epilogue: FC on h_31 (lives in buf[32&1=0])
    do_fc(T_STEPS - 1, 0);
}

extern "C" void kernel_launch(void* const* d_in, const int* in_sizes, int n_in,
                              void* d_out, int out_size, void* d_ws, size_t ws_size,
                              hipStream_t stream) {
    const float* feats = (const float*)d_in[0];
    const float* W_ih  = (const float*)d_in[1];
    const float* W_hh  = (const float*)d_in[2];
    const float* b_ih  = (const float*)d_in[3];
    const float* b_hh  = (const float*)d_in[4];
    const float* fc_w  = (const float*)d_in[5];
    const float* fc_b  = (const float*)d_in[6];
    float* out = (float*)d_out;

    lstmconv_mfma<<<NBLK, NTHR, 0, stream>>>(feats, W_ih, W_hh, b_ih, b_hh,
                                             fc_w, fc_b, out);
}

// Round 4
// 196.947 us; speedup vs baseline: 1.1828x; 1.1828x over previous
//
#include <hip/hip_runtime.h>
#include <stdint.h>

// LSTMConv via MFMA, fragment-major LDS, single barrier per step.
// gates(512x64) = W(512x192) @ [x;h](192x64), mfma_f32_16x16x32_bf16.
// Gate W + FC W persistent in VGPRs. x and h stored in LDS PRE-PACKED as
// MFMA B-fragments (tile-major, lane*16B) -> all LDS reads are
// conflict-free ds_read_b128; gather writes are one ds_write_b128/thread;
// h writes are 2-way (free) b64. Double-buffered -> ONE barrier/step.
// Step t: [issue gather x_{t+1}] [F(t-1) from hB[cur]] [A from xB/hB[cur]]
//         [U -> hB[nxt]] [pack x_{t+1} -> xB[nxt]] [barrier].

#define T_STEPS 32
#define C_IN    64
#define HID     128
#define OUT_F   64
#define BP      64
#define NBLK    256            // 16384 / BP
#define NTHR    512            // 8 waves

typedef __attribute__((ext_vector_type(8))) short short8_t;
typedef __attribute__((ext_vector_type(4))) short short4_t;
typedef __attribute__((ext_vector_type(4))) float float4_t;
typedef __attribute__((ext_vector_type(4))) unsigned int uint4_t;

__device__ __forceinline__ short f2bf(float f) {
    uint32_t u = __builtin_bit_cast(uint32_t, f);
    u += 0x7fff + ((u >> 16) & 1);   // RNE
    return (short)(u >> 16);
}
__device__ __forceinline__ uint32_t cvt_pk(float lo, float hi) {
    uint32_t r;
    asm("v_cvt_pk_bf16_f32 %0, %1, %2" : "=v"(r) : "v"(lo), "v"(hi));
    return r;   // low 16 = bf16(lo), high 16 = bf16(hi)
}
__device__ __forceinline__ float sigm(float x) {
    return __builtin_amdgcn_rcpf(1.0f + __expf(-x));
}
__device__ __forceinline__ float tanh_(float x) {
    float ax = fabsf(x);
    float e  = __expf(-2.0f * ax);
    float t  = (1.0f - e) * __builtin_amdgcn_rcpf(1.0f + e);
    return copysignf(t, x);
}

__global__ __launch_bounds__(NTHR, 2) void lstmconv_mfma(
    const float* __restrict__ feats,
    const float* __restrict__ W_ih,
    const float* __restrict__ W_hh,
    const float* __restrict__ b_ih,
    const float* __restrict__ b_hh,
    const float* __restrict__ fc_w,
    const float* __restrict__ fc_b,
    float* __restrict__ out)
{
    // B-fragment-major LDS: tile = kt*4+nt, within tile: lane*8 shorts (16B).
    __shared__ __align__(16) short xB[2][8][512];    // 16 KB  (x: kt 0..1)
    __shared__ __align__(16) short hB[2][16][512];   // 32 KB  (h: kt2 0..3)
    __shared__ __align__(16) float bias_s[4 * HID];  // 2 KB

    const int tid  = threadIdx.x;
    const int lane = tid & 63;
    const int wv   = tid >> 6;       // wave 0..7; owns gate rows 16wv..16wv+16
    const int i16  = lane & 15;
    const int g4   = lane >> 4;
    const int p0   = blockIdx.x * BP;

    // ---------- one-time init ----------
    for (int i = tid; i < 2 * 16 * 512 / 2; i += NTHR)
        ((uint32_t*)hB)[i] = 0u;                     // h_{-1} = 0
    bias_s[tid] = b_ih[tid] + b_hh[tid];             // 512 == NTHR

    // Gate-W A-fragments, persistent: wfrag[gate][ktile]
    // row = 128*gi + 16*wv + i16 ; k = 32*kt + 8*g4 + e  (kt<2 -> W_ih)
    short8_t wfrag[4][6];
    #pragma unroll
    for (int gi = 0; gi < 4; ++gi) {
        int row = 128 * gi + 16 * wv + i16;
        #pragma unroll
        for (int kt = 0; kt < 6; ++kt) {
            int kk = 32 * kt + 8 * g4;
            const float* src = (kt < 2) ? &W_ih[row * C_IN + kk]
                                        : &W_hh[row * HID + (kk - 64)];
            short8_t f;
            #pragma unroll
            for (int e = 0; e < 8; ++e) f[e] = f2bf(src[e]);
            wfrag[gi][kt] = f;
        }
    }

    // FC: wave handles out rows 16*m2..+16 (m2=wv&3), n-tiles {ntb, ntb+1}.
    const int m2  = wv & 3;
    const int ntb = (wv >> 2) << 1;
    short8_t fcfrag[4];
    #pragma unroll
    for (int kt = 0; kt < 4; ++kt) {
        int kk = 32 * kt + 8 * g4;
        const float* src = &fc_w[(16 * m2 + i16) * HID + kk];
        short8_t f;
        #pragma unroll
        for (int e = 0; e < 8; ++e) f[e] = f2bf(src[e]);
        fcfrag[kt] = f;
    }
    const float4_t fcb = *(const float4_t*)&fc_b[16 * m2 + 4 * g4];

    // gather addressing: thread loads channels c = 8*wv + e, pixel p = lane
    const int prow  = 2 * (p0 >> 7) + 1;
    const int pcol0 = 2 * (p0 & 127) + 1;
    const int gbase = prow * 256 + pcol0 + 2 * lane;
    // destination fragment slot for this thread's 8-channel run:
    const int xtile = (wv >> 2) * 4 + (lane >> 4);           // kt*4 + nt
    const int xoff  = ((lane & 15) + 16 * (wv & 3)) * 8;     // lane'*8
    // h-write slot: thread owns h[p=16nt+i16][j=16wv+4g4+r]
    const int htile_base = (wv >> 1) * 4;                    // + nt
    const int hoff  = (i16 + 16 * (2 * (wv & 1) + (g4 >> 1))) * 8 + 4 * (g4 & 1);

    // ---------- prologue: gather x_0 -> xB[0] ----------
    {
        float g[8];
        #pragma unroll
        for (int e = 0; e < 8; ++e)
            g[e] = feats[((size_t)(8 * wv + e) << 16) + gbase];
        uint4_t pk = { cvt_pk(g[0], g[1]), cvt_pk(g[2], g[3]),
                       cvt_pk(g[4], g[5]), cvt_pk(g[6], g[7]) };
        *(uint4_t*)&xB[0][xtile][xoff] = pk;
    }

    float4_t c[4];
    #pragma unroll
    for (int nt = 0; nt < 4; ++nt) c[nt] = (float4_t){0.f, 0.f, 0.f, 0.f};

    // FC + store for step tf, reading h B-frags from hB[cb]
    auto do_fc = [&](int tf, int cb) {
        float4_t facc[2];
        facc[0] = fcb; facc[1] = fcb;
        #pragma unroll
        for (int kt = 0; kt < 4; ++kt) {
            #pragma unroll
            for (int nj = 0; nj < 2; ++nj) {
                short8_t b = *(const short8_t*)&hB[cb][kt * 4 + ntb + nj][lane * 8];
                facc[nj] = __builtin_amdgcn_mfma_f32_16x16x32_bf16(
                    fcfrag[kt], b, facc[nj], 0, 0, 0);
            }
        }
        #pragma unroll
        for (int nj = 0; nj < 2; ++nj)
            #pragma unroll
            for (int r = 0; r < 4; ++r)
                out[((size_t)(tf * OUT_F + 16 * m2 + 4 * g4 + r) << 14)
                    + p0 + 16 * (ntb + nj) + i16] = facc[nj][r];
    };

    __syncthreads();   // xB[0] ready, hB zeroed

    #pragma unroll 1
    for (int t = 0; t < T_STEPS; ++t) {
        const int cur = t & 1;
        const int nxt = cur ^ 1;

        // ---- issue gather loads for x_{t+1}
        float g[8];
        if (t < T_STEPS - 1) {
            #pragma unroll
            for (int e = 0; e < 8; ++e)
                g[e] = feats[((size_t)((t + 1) * C_IN + 8 * wv + e) << 16) + gbase];
        }

        // ---- F(t-1): FC on h_{t-1} (in hB[cur])
        if (t > 0) do_fc(t - 1, cur);

        // ---- A: gates = bias + W @ [x_t; h_{t-1}]  (all reads b128, conflict-free)
        float4_t acc[4][4];
        #pragma unroll
        for (int gi = 0; gi < 4; ++gi) {
            float4_t bv = *(const float4_t*)&bias_s[128 * gi + 16 * wv + 4 * g4];
            #pragma unroll
            for (int nt = 0; nt < 4; ++nt) acc[gi][nt] = bv;
        }
        #pragma unroll
        for (int kt = 0; kt < 6; ++kt) {
            short8_t bfrag[4];
            #pragma unroll
            for (int nt = 0; nt < 4; ++nt) {
                const short* src = (kt < 2) ? &xB[cur][kt * 4 + nt][0]
                                            : &hB[cur][(kt - 2) * 4 + nt][0];
                bfrag[nt] = *(const short8_t*)&src[lane * 8];
            }
            #pragma unroll
            for (int gi = 0; gi < 4; ++gi)
                #pragma unroll
                for (int nt = 0; nt < 4; ++nt)
                    acc[gi][nt] = __builtin_amdgcn_mfma_f32_16x16x32_bf16(
                        wfrag[gi][kt], bfrag[nt], acc[gi][nt], 0, 0, 0);
        }

        // ---- U: cell update (gate order i,f,g,o) + h_t -> hB[nxt]
        #pragma unroll
        for (int nt = 0; nt < 4; ++nt) {
            float4_t cv = c[nt];
            float hv[4];
            #pragma unroll
            for (int r = 0; r < 4; ++r) {
                float ig = sigm(acc[0][nt][r]);
                float fg = sigm(acc[1][nt][r]);
                float gg = tanh_(acc[2][nt][r]);
                float og = sigm(acc[3][nt][r]);
                float cn = fg * cv[r] + ig * gg;
                cv[r] = cn;
                hv[r] = og * tanh_(cn);
            }
            c[nt] = cv;
            uint32_t h0 = cvt_pk(hv[0], hv[1]);
            uint32_t h1 = cvt_pk(hv[2], hv[3]);
            uint32_t* dst = (uint32_t*)&hB[nxt][htile_base + nt][hoff];
            dst[0] = h0; dst[1] = h1;          // 8B aligned -> b64 write
        }

        // ---- pack & store x_{t+1} -> xB[nxt] (one b128 write)
        if (t < T_STEPS - 1) {
            uint4_t pk = { cvt_pk(g[0], g[1]), cvt_pk(g[2], g[3]),
                           cvt_pk(g[4], g[5]), cvt_pk(g[6], g[7]) };
            *(uint4_t*)&xB[nxt][xtile][xoff] = pk;
        }

        __syncthreads();   // buf[nxt] = {x_{t+1}, h_t} complete
    }

    // epilogue: FC on h_31 (written to hB[0] during t=31)
    do_fc(T_STEPS - 1, 0);
}

extern "C" void kernel_launch(void* const* d_in, const int* in_sizes, int n_in,
                              void* d_out, int out_size, void* d_ws, size_t ws_size,
                              hipStream_t stream) {
    const float* feats = (const float*)d_in[0];
    const float* W_ih  = (const float*)d_in[1];
    const float* W_hh  = (const float*)d_in[2];
    const float* b_ih  = (const float*)d_in[3];
    const float* b_hh  = (const float*)d_in[4];
    const float* fc_w  = (const float*)d_in[5];
    const float* fc_b  = (const float*)d_in[6];
    float* out = (float*)d_out;

    lstmconv_mfma<<<NBLK, NTHR, 0, stream>>>(feats, W_ih, W_hh, b_ih, b_hh,
                                             fc_w, fc_b, out);
}